// Round 2
// baseline (444.099 us; speedup 1.0000x reference)
//
#include <hip/hip_runtime.h>

// Problem constants: B=16, H=90, LP=512, W=256, L=256, K=384
#define B_     16
#define H_     90
#define LP_    512
#define WL_    65536        // W*L
#define K_     384
#define BHK    (B_ * H_ * K_)   // 552960
#define HG     3            // h-rows per mse block
#define NH     (H_ / HG)    // 30 h-groups

// K1: fused selection — stable compaction of mask -> pos, one block per batch.
// 1024 threads scan the batch's 65536 mask ints in 16 coalesced int4 slices
// (slice i: threads read ints [i*4096 + 4t .. +3], perfectly coalesced).
// Rank = wave shfl-scan + cross-wave/cross-slice LDS scan (broadcast reads,
// no bank conflicts), ONE barrier. Also zeroes the output scalar.
__global__ __launch_bounds__(1024) void select_kernel(const int* __restrict__ mask,
                                                      int* __restrict__ pos,
                                                      float* __restrict__ out) {
    const int b = blockIdx.x;
    const int t = threadIdx.x;
    if (b == 0 && t == 0) out[0] = 0.0f;
    const int lane = t & 63, wid = t >> 6;

    __shared__ int ws[16][16];          // [slice][wave] inclusive wave totals
    unsigned long long fl = 0ull;       // 4 flag bits per slice
    int wexcl[16];                      // per-slice exclusive rank within wave

    const int4* __restrict__ src = (const int4*)(mask + (size_t)b * WL_);
    #pragma unroll
    for (int i = 0; i < 16; ++i) {
        const int4 v = src[i * 1024 + t];
        const int f0 = v.x != 0, f1 = v.y != 0, f2 = v.z != 0, f3 = v.w != 0;
        fl |= (unsigned long long)(f0 | (f1 << 1) | (f2 << 2) | (f3 << 3)) << (i * 4);
        const int c = f0 + f1 + f2 + f3;
        int incl = c;
        #pragma unroll
        for (int d = 1; d < 64; d <<= 1) {
            const int x = __shfl_up(incl, d, 64);
            if (lane >= d) incl += x;
        }
        if (lane == 63) ws[i][wid] = incl;
        wexcl[i] = incl - c;
    }
    __syncthreads();

    int* __restrict__ pb = pos + b * K_;
    int running = 0;                    // selected count in slices < i
    #pragma unroll
    for (int i = 0; i < 16; ++i) {
        int wbase = 0, tot = 0;
        #pragma unroll
        for (int w = 0; w < 16; ++w) {  // wave-uniform LDS reads -> broadcast
            const int x = ws[i][w];
            tot += x;
            if (w < wid) wbase += x;
        }
        int wp = running + wbase + wexcl[i];   // this thread's first rank in slice i
        running += tot;
        const int gb = i * 4096 + t * 4;       // position within batch row
        if ((fl >> (i * 4 + 0)) & 1) pb[wp++] = gb + 0;
        if ((fl >> (i * 4 + 1)) & 1) pb[wp++] = gb + 1;
        if ((fl >> (i * 4 + 2)) & 1) pb[wp++] = gb + 2;
        if ((fl >> (i * 4 + 3)) & 1) pb[wp]   = gb + 3;
    }
}

// K2: MSE. One block per (b, group of HG=3 h-rows), 384 threads (= K_),
// thread k handles col k of all 3 rows: pos load amortized 3x, 3 independent
// HBM gathers in flight per lane (ILP vs the ~900-cycle miss latency),
// atomics 1440 -> 480.
__global__ __launch_bounds__(384) void mse_kernel(const float* __restrict__ cs,
                                                  const float* __restrict__ csp,
                                                  const int* __restrict__ pos,
                                                  float* __restrict__ out) {
    const int g  = blockIdx.x;                 // 0..B_*NH-1 = 480
    const int b  = g / NH;
    const int h0 = (g - b * NH) * HG;
    const int k  = threadIdx.x;                // 0..383 (< LP_, non-NaN cols)
    const int p  = pos[b * K_ + k];            // L2-hot, shared across h
    const size_t r0 = (size_t)(b * H_ + h0);
    float acc = 0.0f;
    #pragma unroll
    for (int j = 0; j < HG; ++j) {
        const float a = cs [(r0 + j) * LP_ + k];
        const float c = csp[(r0 + j) * WL_ + p];
        const float d = a - c;
        acc = fmaf(d, d, acc);
    }
    #pragma unroll
    for (int off = 32; off > 0; off >>= 1) acc += __shfl_down(acc, off, 64);
    __shared__ float s[6];
    const int lane = k & 63, wid = k >> 6;
    if (lane == 0) s[wid] = acc;
    __syncthreads();
    if (k == 0) {
        const float sum = s[0] + s[1] + s[2] + s[3] + s[4] + s[5];
        atomicAdd(out, sum * (1.0f / (float)BHK));
    }
}

extern "C" void kernel_launch(void* const* d_in, const int* in_sizes, int n_in,
                              void* d_out, int out_size, void* d_ws, size_t ws_size,
                              hipStream_t stream) {
    const float* cs   = (const float*)d_in[0];   // (B, H, LP) f32
    const float* csp  = (const float*)d_in[1];   // (B, H, W, L) f32
    const int*   mask = (const int*)d_in[2];     // (B, W, L) i32, exactly K ones/batch
    float* out = (float*)d_out;                  // scalar f32

    int* pos = (int*)d_ws;                       // B_*K_ = 6144 ints

    select_kernel<<<B_,      1024, 0, stream>>>(mask, pos, out);
    mse_kernel   <<<B_ * NH,  384, 0, stream>>>(cs, csp, pos, out);
}